// Round 2
// baseline (1317.866 us; speedup 1.0000x reference)
//
#include <hip/hip_runtime.h>

#define NPOS 512
#define NN_ (512 * 512)

typedef unsigned short u16;

__device__ __forceinline__ float bf2f(u16 u) {
  union { unsigned int i; float f; } v;
  v.i = ((unsigned int)u) << 16;
  return v.f;
}
__device__ __forceinline__ u16 f2bf(float f) {
  unsigned int u = __float_as_uint(f);
  unsigned int r = (u + 0x7fffu + ((u >> 16) & 1u)) >> 16;
  return (u16)r;
}
__device__ __forceinline__ float sigm(float x) { return 1.0f / (1.0f + __expf(-x)); }

// ---------------------------------------------------------------------------
// K1: input LayerNorm over C=128. One wave (64 lanes) per position, 2 vals/lane.
// ---------------------------------------------------------------------------
__global__ __launch_bounds__(256) void k1_ln(const float* __restrict__ act,
                                             const float* __restrict__ g,
                                             const float* __restrict__ b,
                                             u16* __restrict__ xln) {
  int wave = threadIdx.x >> 6, lane = threadIdx.x & 63;
  size_t p = (size_t)blockIdx.x * 4 + wave;
  const float* row = act + p * 128;
  float2 v = *(const float2*)(row + lane * 2);
  float s = v.x + v.y;
  float ss = v.x * v.x + v.y * v.y;
#pragma unroll
  for (int m = 32; m; m >>= 1) {
    s += __shfl_xor(s, m);
    ss += __shfl_xor(ss, m);
  }
  float mu = s * (1.0f / 128.0f);
  float rstd = rsqrtf(ss * (1.0f / 128.0f) - mu * mu + 1e-5f);
  float y0 = (v.x - mu) * rstd * g[lane * 2] + b[lane * 2];
  float y1 = (v.y - mu) * rstd * g[lane * 2 + 1] + b[lane * 2 + 1];
  ushort2 o;
  o.x = f2bf(y0);
  o.y = f2bf(y1);
  *(ushort2*)(xln + p * 128 + lane * 2) = o;
}

// ---------------------------------------------------------------------------
// K2 (pair): for a 64-position tile, compute proj = x@Wp+Bp and gate = x@Wg+Bg,
// val = mask * proj * sigmoid(gate), store transposed to Tout[c][i][k] (bf16).
// W staged in bf16 halves (64 outs) to keep LDS at ~49.5KB (3 blocks/CU).
// ---------------------------------------------------------------------------
__global__ __launch_bounds__(256) void k2_pair(const u16* __restrict__ xln,
                                               const float* __restrict__ mask,
                                               const float* __restrict__ Wp,
                                               const float* __restrict__ Bp,
                                               const float* __restrict__ Wg,
                                               const float* __restrict__ Bg,
                                               u16* __restrict__ Tout) {
  __shared__ __align__(16) unsigned char smem[49664];
  u16* xl = (u16*)smem;                  // [128][66] bf16
  u16* w0 = (u16*)(smem + 16896);        // [128][64] bf16
  u16* w1 = (u16*)(smem + 33280);        // [128][64] bf16
  u16* tb = w0;                          // [64][68] bf16, reuses w0 region

  int tid = threadIdx.x;
  size_t p0 = (size_t)blockIdx.x * 64;
  int i_row = (int)(p0 >> 9);
  int kk0 = (int)(p0 & 511);

  // stage x: read [64 pos][128 c] bf16 coalesced, write xl[c][pos]
#pragma unroll
  for (int it = 0; it < 8; ++it) {
    int l = it * 256 + tid;
    int pos = l >> 5, c4 = l & 31;
    ushort4 v = *(const ushort4*)(xln + (p0 + pos) * 128 + c4 * 4);
    xl[(c4 * 4 + 0) * 66 + pos] = v.x;
    xl[(c4 * 4 + 1) * 66 + pos] = v.y;
    xl[(c4 * 4 + 2) * 66 + pos] = v.z;
    xl[(c4 * 4 + 3) * 66 + pos] = v.w;
  }

  int tx = tid & 15, ty = tid >> 4;

  for (int h = 0; h < 2; ++h) {
    __syncthreads();
    // stage W halves (f32 global -> bf16 LDS)
#pragma unroll
    for (int it = 0; it < 8; ++it) {
      int l = it * 256 + tid;
      int k = l >> 4, o4 = l & 15;
      float4 a = *(const float4*)(Wp + k * 128 + h * 64 + o4 * 4);
      ushort4 u;
      u.x = f2bf(a.x); u.y = f2bf(a.y); u.z = f2bf(a.z); u.w = f2bf(a.w);
      *(ushort4*)(w0 + k * 64 + o4 * 4) = u;
      float4 c = *(const float4*)(Wg + k * 128 + h * 64 + o4 * 4);
      ushort4 u2;
      u2.x = f2bf(c.x); u2.y = f2bf(c.y); u2.z = f2bf(c.z); u2.w = f2bf(c.w);
      *(ushort4*)(w1 + k * 64 + o4 * 4) = u2;
    }
    __syncthreads();

    float acc0[4][4] = {{0}};
    float acc1[4][4] = {{0}};
#pragma unroll 8
    for (int k = 0; k < 128; ++k) {
      float a[4];
      ushort2 a0 = *(const ushort2*)(xl + k * 66 + ty * 4);
      ushort2 a1 = *(const ushort2*)(xl + k * 66 + ty * 4 + 2);
      a[0] = bf2f(a0.x); a[1] = bf2f(a0.y); a[2] = bf2f(a1.x); a[3] = bf2f(a1.y);
      ushort4 bv0 = *(const ushort4*)(w0 + k * 64 + tx * 4);
      ushort4 bv1 = *(const ushort4*)(w1 + k * 64 + tx * 4);
      float b0[4] = {bf2f(bv0.x), bf2f(bv0.y), bf2f(bv0.z), bf2f(bv0.w)};
      float b1[4] = {bf2f(bv1.x), bf2f(bv1.y), bf2f(bv1.z), bf2f(bv1.w)};
#pragma unroll
      for (int pp = 0; pp < 4; ++pp) {
#pragma unroll
        for (int oo = 0; oo < 4; ++oo) {
          acc0[pp][oo] = fmaf(a[pp], b0[oo], acc0[pp][oo]);
          acc1[pp][oo] = fmaf(a[pp], b1[oo], acc1[pp][oo]);
        }
      }
    }
    __syncthreads();

    // epilogue: activation, transpose via LDS
    float bp[4], bg[4];
#pragma unroll
    for (int oo = 0; oo < 4; ++oo) {
      bp[oo] = Bp[h * 64 + tx * 4 + oo];
      bg[oo] = Bg[h * 64 + tx * 4 + oo];
    }
#pragma unroll
    for (int pp = 0; pp < 4; ++pp) {
      float mk = mask[p0 + ty * 4 + pp];
#pragma unroll
      for (int oo = 0; oo < 4; ++oo) {
        int o = tx * 4 + oo;
        float val = mk * (acc0[pp][oo] + bp[oo]) * sigm(acc1[pp][oo] + bg[oo]);
        tb[o * 68 + ty * 4 + pp] = f2bf(val);
      }
    }
    __syncthreads();
    // coalesced store: Tout[(h*64+o)][i_row][kk0 + j]
#pragma unroll
    for (int it = 0; it < 4; ++it) {
      int l = it * 256 + tid;
      int o = l >> 4, j4 = l & 15;
      ushort4 v = *(const ushort4*)(tb + o * 68 + j4 * 4);
      *(ushort4*)(Tout + (size_t)(h * 64 + o) * NN_ + (size_t)i_row * 512 + kk0 + j4 * 4) = v;
    }
  }
}

// ---------------------------------------------------------------------------
// K2 (gate): Gs[p][o] = sigmoid(x @ wgate + bgate), position-major bf16.
// ---------------------------------------------------------------------------
__global__ __launch_bounds__(256) void k2_gate(const u16* __restrict__ xln,
                                               const float* __restrict__ Wg,
                                               const float* __restrict__ Bg,
                                               u16* __restrict__ Gs) {
  __shared__ __align__(16) unsigned char smem[16896 + 32768];
  u16* xl = (u16*)smem;             // [128][66]
  u16* wb = (u16*)(smem + 16896);   // [128][128]

  int tid = threadIdx.x;
  size_t p0 = (size_t)blockIdx.x * 64;

#pragma unroll
  for (int it = 0; it < 8; ++it) {
    int l = it * 256 + tid;
    int pos = l >> 5, c4 = l & 31;
    ushort4 v = *(const ushort4*)(xln + (p0 + pos) * 128 + c4 * 4);
    xl[(c4 * 4 + 0) * 66 + pos] = v.x;
    xl[(c4 * 4 + 1) * 66 + pos] = v.y;
    xl[(c4 * 4 + 2) * 66 + pos] = v.z;
    xl[(c4 * 4 + 3) * 66 + pos] = v.w;
  }
#pragma unroll
  for (int it = 0; it < 16; ++it) {
    int l = it * 256 + tid;
    int k = l >> 5, o4 = l & 31;
    float4 a = *(const float4*)(Wg + k * 128 + o4 * 4);
    ushort4 u;
    u.x = f2bf(a.x); u.y = f2bf(a.y); u.z = f2bf(a.z); u.w = f2bf(a.w);
    *(ushort4*)(wb + k * 128 + o4 * 4) = u;
  }
  __syncthreads();

  int tx = tid & 15, ty = tid >> 4;
  float acc[4][8] = {{0}};
#pragma unroll 8
  for (int k = 0; k < 128; ++k) {
    float a[4];
    ushort2 a0 = *(const ushort2*)(xl + k * 66 + ty * 4);
    ushort2 a1 = *(const ushort2*)(xl + k * 66 + ty * 4 + 2);
    a[0] = bf2f(a0.x); a[1] = bf2f(a0.y); a[2] = bf2f(a1.x); a[3] = bf2f(a1.y);
    ushort4 b0 = *(const ushort4*)(wb + k * 128 + tx * 8);
    ushort4 b1 = *(const ushort4*)(wb + k * 128 + tx * 8 + 4);
    float b[8] = {bf2f(b0.x), bf2f(b0.y), bf2f(b0.z), bf2f(b0.w),
                  bf2f(b1.x), bf2f(b1.y), bf2f(b1.z), bf2f(b1.w)};
#pragma unroll
    for (int pp = 0; pp < 4; ++pp)
#pragma unroll
      for (int oo = 0; oo < 8; ++oo)
        acc[pp][oo] = fmaf(a[pp], b[oo], acc[pp][oo]);
  }
  float bg[8];
#pragma unroll
  for (int oo = 0; oo < 8; ++oo) bg[oo] = Bg[tx * 8 + oo];
#pragma unroll
  for (int pp = 0; pp < 4; ++pp) {
    size_t p = p0 + ty * 4 + pp;
    ushort4 v0, v1;
    v0.x = f2bf(sigm(acc[pp][0] + bg[0]));
    v0.y = f2bf(sigm(acc[pp][1] + bg[1]));
    v0.z = f2bf(sigm(acc[pp][2] + bg[2]));
    v0.w = f2bf(sigm(acc[pp][3] + bg[3]));
    v1.x = f2bf(sigm(acc[pp][4] + bg[4]));
    v1.y = f2bf(sigm(acc[pp][5] + bg[5]));
    v1.z = f2bf(sigm(acc[pp][6] + bg[6]));
    v1.w = f2bf(sigm(acc[pp][7] + bg[7]));
    *(ushort4*)(Gs + p * 128 + tx * 8) = v0;
    *(ushort4*)(Gs + p * 128 + tx * 8 + 4) = v1;
  }
}

// ---------------------------------------------------------------------------
// K3: per-channel NT GEMM: Ot[c][i][j] = sum_k Lt[c][i][k] * Rt[c][j][k].
// 64x64 output tile per block, BK=32, bf16 global -> f32 LDS -> f32 FMA.
// ---------------------------------------------------------------------------
__global__ __launch_bounds__(256) void k3_einsum(const u16* __restrict__ Lt,
                                                 const u16* __restrict__ Rt,
                                                 u16* __restrict__ Ot) {
  __shared__ __align__(16) float smem[2 * 32 * 68];
  float* Ll = smem;            // [32][68]
  float* Rl = smem + 32 * 68;  // [32][68]

  int bx = blockIdx.x;
  int c = bx >> 6;
  int t = bx & 63;
  int i0 = (t >> 3) * 64, j0 = (t & 7) * 64;
  int tid = threadIdx.x;
  int tx = tid & 15, ty = tid >> 4;
  int r = tid >> 2, kq = tid & 3;
  const u16* Lg = Lt + (size_t)c * NN_;
  const u16* Rg = Rt + (size_t)c * NN_;

  float acc[4][4] = {{0}};
  for (int kt = 0; kt < 512; kt += 32) {
    ushort4 lv0 = *(const ushort4*)(Lg + (size_t)(i0 + r) * 512 + kt + kq * 8);
    ushort4 lv1 = *(const ushort4*)(Lg + (size_t)(i0 + r) * 512 + kt + kq * 8 + 4);
    ushort4 rv0 = *(const ushort4*)(Rg + (size_t)(j0 + r) * 512 + kt + kq * 8);
    ushort4 rv1 = *(const ushort4*)(Rg + (size_t)(j0 + r) * 512 + kt + kq * 8 + 4);
    __syncthreads();  // previous iteration's reads complete
    Ll[(kq * 8 + 0) * 68 + r] = bf2f(lv0.x);
    Ll[(kq * 8 + 1) * 68 + r] = bf2f(lv0.y);
    Ll[(kq * 8 + 2) * 68 + r] = bf2f(lv0.z);
    Ll[(kq * 8 + 3) * 68 + r] = bf2f(lv0.w);
    Ll[(kq * 8 + 4) * 68 + r] = bf2f(lv1.x);
    Ll[(kq * 8 + 5) * 68 + r] = bf2f(lv1.y);
    Ll[(kq * 8 + 6) * 68 + r] = bf2f(lv1.z);
    Ll[(kq * 8 + 7) * 68 + r] = bf2f(lv1.w);
    Rl[(kq * 8 + 0) * 68 + r] = bf2f(rv0.x);
    Rl[(kq * 8 + 1) * 68 + r] = bf2f(rv0.y);
    Rl[(kq * 8 + 2) * 68 + r] = bf2f(rv0.z);
    Rl[(kq * 8 + 3) * 68 + r] = bf2f(rv0.w);
    Rl[(kq * 8 + 4) * 68 + r] = bf2f(rv1.x);
    Rl[(kq * 8 + 5) * 68 + r] = bf2f(rv1.y);
    Rl[(kq * 8 + 6) * 68 + r] = bf2f(rv1.z);
    Rl[(kq * 8 + 7) * 68 + r] = bf2f(rv1.w);
    __syncthreads();
#pragma unroll
    for (int kk = 0; kk < 32; ++kk) {
      float av[4], bv[4];
      *(float4*)av = *(const float4*)(Ll + kk * 68 + ty * 4);
      *(float4*)bv = *(const float4*)(Rl + kk * 68 + tx * 4);
#pragma unroll
      for (int ii = 0; ii < 4; ++ii)
#pragma unroll
        for (int jj = 0; jj < 4; ++jj)
          acc[ii][jj] = fmaf(av[ii], bv[jj], acc[ii][jj]);
    }
  }
#pragma unroll
  for (int ii = 0; ii < 4; ++ii) {
    ushort4 v;
    v.x = f2bf(acc[ii][0]);
    v.y = f2bf(acc[ii][1]);
    v.z = f2bf(acc[ii][2]);
    v.w = f2bf(acc[ii][3]);
    *(ushort4*)(Ot + (size_t)c * NN_ + (size_t)(i0 + ty * 4 + ii) * 512 + j0 + tx * 4) = v;
  }
}

// ---------------------------------------------------------------------------
// K4: center LN over MID + out = LN(.) @ wout + bout, times precomputed
// sigmoid(gate). 64 positions x 128 outs per block.
// ---------------------------------------------------------------------------
__global__ __launch_bounds__(256) void k4_out(const u16* __restrict__ Ot,
                                              const u16* __restrict__ Gs,
                                              const float* __restrict__ gc,
                                              const float* __restrict__ bc,
                                              const float* __restrict__ wout,
                                              const float* __restrict__ bout,
                                              float* __restrict__ out) {
  __shared__ __align__(16) unsigned char smem[34816 + 32768];
  float* xm = (float*)smem;               // [128][68] f32
  u16* ot = (u16*)(smem + 34816);         // [128][64] bf16
  u16* wb = (u16*)(smem + 34816);         // [128][128] bf16 (after LN phase)

  int tid = threadIdx.x;
  size_t p0 = (size_t)blockIdx.x * 64;
  int i_row = (int)(p0 >> 9);
  int j0 = (int)(p0 & 511);

  // P1: gather Ot[:, i_row, j0:j0+64]
#pragma unroll
  for (int it = 0; it < 8; ++it) {
    int l = it * 256 + tid;
    int cc = l >> 4, j4 = l & 15;
    ushort4 v = *(const ushort4*)(Ot + (size_t)cc * NN_ + (size_t)i_row * 512 + j0 + j4 * 4);
    *(ushort4*)(ot + cc * 64 + j4 * 4) = v;
  }
  __syncthreads();

  // P2: LayerNorm over 128 channels; 4 threads per position
  {
    int pos = tid >> 2, q = tid & 3;
    float s = 0.0f, ss = 0.0f;
    float vals[32];
#pragma unroll
    for (int m = 0; m < 32; ++m) {
      float v = bf2f(ot[(q * 32 + m) * 64 + pos]);
      vals[m] = v;
      s += v;
      ss += v * v;
    }
    s += __shfl_xor(s, 1); ss += __shfl_xor(ss, 1);
    s += __shfl_xor(s, 2); ss += __shfl_xor(ss, 2);
    float mu = s * (1.0f / 128.0f);
    float rstd = rsqrtf(ss * (1.0f / 128.0f) - mu * mu + 1e-5f);
#pragma unroll
    for (int m = 0; m < 32; ++m) {
      int cc = q * 32 + m;
      xm[cc * 68 + pos] = (vals[m] - mu) * rstd * gc[cc] + bc[cc];
    }
  }
  __syncthreads();

  // P3a: stage wout as bf16 (overwrites ot region)  [FIX: it<16, was it<8 —
  // rows 64..127 of wb were uninitialized LDS -> NaN]
#pragma unroll
  for (int it = 0; it < 16; ++it) {
    int l = it * 256 + tid;
    int k = l >> 5, o4 = l & 31;
    float4 a = *(const float4*)(wout + k * 128 + o4 * 4);
    ushort4 u;
    u.x = f2bf(a.x); u.y = f2bf(a.y); u.z = f2bf(a.z); u.w = f2bf(a.w);
    *(ushort4*)(wb + k * 128 + o4 * 4) = u;
  }
  __syncthreads();

  // P3b: GEMM 64 pos x 128 outs
  int tx = tid & 15, ty = tid >> 4;
  float acc[4][8] = {{0}};
#pragma unroll 8
  for (int k = 0; k < 128; ++k) {
    float av[4];
    *(float4*)av = *(const float4*)(xm + k * 68 + ty * 4);
    ushort4 b0 = *(const ushort4*)(wb + k * 128 + tx * 8);
    ushort4 b1 = *(const ushort4*)(wb + k * 128 + tx * 8 + 4);
    float b[8] = {bf2f(b0.x), bf2f(b0.y), bf2f(b0.z), bf2f(b0.w),
                  bf2f(b1.x), bf2f(b1.y), bf2f(b1.z), bf2f(b1.w)};
#pragma unroll
    for (int pp = 0; pp < 4; ++pp)
#pragma unroll
      for (int oo = 0; oo < 8; ++oo)
        acc[pp][oo] = fmaf(av[pp], b[oo], acc[pp][oo]);
  }
  float bo[8];
#pragma unroll
  for (int oo = 0; oo < 8; ++oo) bo[oo] = bout[tx * 8 + oo];
#pragma unroll
  for (int pp = 0; pp < 4; ++pp) {
    size_t p = p0 + ty * 4 + pp;
    ushort4 g0 = *(const ushort4*)(Gs + p * 128 + tx * 8);
    ushort4 g1 = *(const ushort4*)(Gs + p * 128 + tx * 8 + 4);
    float y[8];
    y[0] = (acc[pp][0] + bo[0]) * bf2f(g0.x);
    y[1] = (acc[pp][1] + bo[1]) * bf2f(g0.y);
    y[2] = (acc[pp][2] + bo[2]) * bf2f(g0.z);
    y[3] = (acc[pp][3] + bo[3]) * bf2f(g0.w);
    y[4] = (acc[pp][4] + bo[4]) * bf2f(g1.x);
    y[5] = (acc[pp][5] + bo[5]) * bf2f(g1.y);
    y[6] = (acc[pp][6] + bo[6]) * bf2f(g1.z);
    y[7] = (acc[pp][7] + bo[7]) * bf2f(g1.w);
    float4 f0 = {y[0], y[1], y[2], y[3]};
    float4 f1 = {y[4], y[5], y[6], y[7]};
    *(float4*)(out + p * 128 + tx * 8) = f0;
    *(float4*)(out + p * 128 + tx * 8 + 4) = f1;
  }
}

// ---------------------------------------------------------------------------
extern "C" void kernel_launch(void* const* d_in, const int* in_sizes, int n_in,
                              void* d_out, int out_size, void* d_ws, size_t ws_size,
                              hipStream_t stream) {
  const float* act    = (const float*)d_in[0];
  const float* mask   = (const float*)d_in[1];
  const float* ln_in_g = (const float*)d_in[2];
  const float* ln_in_b = (const float*)d_in[3];
  const float* wl     = (const float*)d_in[4];
  const float* bl     = (const float*)d_in[5];
  const float* wr     = (const float*)d_in[6];
  const float* br     = (const float*)d_in[7];
  const float* wgl    = (const float*)d_in[8];
  const float* bgl    = (const float*)d_in[9];
  const float* wgr    = (const float*)d_in[10];
  const float* bgr    = (const float*)d_in[11];
  const float* wgate  = (const float*)d_in[12];
  const float* bgate  = (const float*)d_in[13];
  const float* ln_c_g = (const float*)d_in[14];
  const float* ln_c_b = (const float*)d_in[15];
  const float* wout   = (const float*)d_in[16];
  const float* bout   = (const float*)d_in[17];
  float* out = (float*)d_out;

  char* ws = (char*)d_ws;
  const size_t SEG = 1ull << 26;  // 64 MiB per bf16 [128][512][512] buffer
  u16* Lt  = (u16*)(ws);
  u16* Rt  = (u16*)(ws + 1 * SEG);
  u16* Gs  = (u16*)(ws + 2 * SEG);
  u16* Ot  = (u16*)(ws + 3 * SEG);
  u16* xln = Ot;  // alias: xln lifetime [K1,K2], Ot lifetime [K3,K4]

  k1_ln<<<dim3(65536), dim3(256), 0, stream>>>(act, ln_in_g, ln_in_b, xln);
  k2_pair<<<dim3(4096), dim3(256), 0, stream>>>(xln, mask, wl, bl, wgl, bgl, Lt);
  k2_pair<<<dim3(4096), dim3(256), 0, stream>>>(xln, mask, wr, br, wgr, bgr, Rt);
  k2_gate<<<dim3(4096), dim3(256), 0, stream>>>(xln, wgate, bgate, Gs);
  k3_einsum<<<dim3(8192), dim3(256), 0, stream>>>(Lt, Rt, Ot);
  k4_out<<<dim3(4096), dim3(256), 0, stream>>>(Ot, Gs, ln_c_g, ln_c_b, wout, bout, out);
}

// Round 3
// 987.673 us; speedup vs baseline: 1.3343x; 1.3343x over previous
//
#include <hip/hip_runtime.h>

#define NPOS 512
#define NN_ (512 * 512)

typedef unsigned short u16;
typedef __attribute__((ext_vector_type(8))) short bf16x8_t;  // 8 bf16 in 4 VGPRs
typedef __attribute__((ext_vector_type(4))) float f32x4_t;   // MFMA acc

__device__ __forceinline__ float bf2f(u16 u) {
  union { unsigned int i; float f; } v;
  v.i = ((unsigned int)u) << 16;
  return v.f;
}
__device__ __forceinline__ u16 f2bf(float f) {
  unsigned int u = __float_as_uint(f);
  unsigned int r = (u + 0x7fffu + ((u >> 16) & 1u)) >> 16;
  return (u16)r;
}
__device__ __forceinline__ float sigm(float x) { return 1.0f / (1.0f + __expf(-x)); }

// async global->LDS, 16B per lane. LDS dest is wave-uniform base + lane*16;
// we pass the per-lane pointer whose value equals exactly that.
__device__ __forceinline__ void gld_lds16(u16* lds, const u16* g) {
  __builtin_amdgcn_global_load_lds(
      (const __attribute__((address_space(1))) unsigned int*)g,
      (__attribute__((address_space(3))) unsigned int*)lds, 16, 0, 0);
}

// ---------------------------------------------------------------------------
// K1: input LayerNorm over C=128. One wave (64 lanes) per position, 2 vals/lane.
// ---------------------------------------------------------------------------
__global__ __launch_bounds__(256) void k1_ln(const float* __restrict__ act,
                                             const float* __restrict__ g,
                                             const float* __restrict__ b,
                                             u16* __restrict__ xln) {
  int wave = threadIdx.x >> 6, lane = threadIdx.x & 63;
  size_t p = (size_t)blockIdx.x * 4 + wave;
  const float* row = act + p * 128;
  float2 v = *(const float2*)(row + lane * 2);
  float s = v.x + v.y;
  float ss = v.x * v.x + v.y * v.y;
#pragma unroll
  for (int m = 32; m; m >>= 1) {
    s += __shfl_xor(s, m);
    ss += __shfl_xor(ss, m);
  }
  float mu = s * (1.0f / 128.0f);
  float rstd = rsqrtf(ss * (1.0f / 128.0f) - mu * mu + 1e-5f);
  float y0 = (v.x - mu) * rstd * g[lane * 2] + b[lane * 2];
  float y1 = (v.y - mu) * rstd * g[lane * 2 + 1] + b[lane * 2 + 1];
  ushort2 o;
  o.x = f2bf(y0);
  o.y = f2bf(y1);
  *(ushort2*)(xln + p * 128 + lane * 2) = o;
}

// ---------------------------------------------------------------------------
// K2 (pair): proj = x@Wp+Bp, gate = x@Wg+Bg, val = mask*proj*sigmoid(gate),
// stored transposed to Tout[c][i][k] (bf16). (VALU version — MFMA next round.)
// ---------------------------------------------------------------------------
__global__ __launch_bounds__(256) void k2_pair(const u16* __restrict__ xln,
                                               const float* __restrict__ mask,
                                               const float* __restrict__ Wp,
                                               const float* __restrict__ Bp,
                                               const float* __restrict__ Wg,
                                               const float* __restrict__ Bg,
                                               u16* __restrict__ Tout) {
  __shared__ __align__(16) unsigned char smem[49664];
  u16* xl = (u16*)smem;                  // [128][66] bf16
  u16* w0 = (u16*)(smem + 16896);        // [128][64] bf16
  u16* w1 = (u16*)(smem + 33280);        // [128][64] bf16
  u16* tb = w0;                          // [64][68] bf16, reuses w0 region

  int tid = threadIdx.x;
  size_t p0 = (size_t)blockIdx.x * 64;
  int i_row = (int)(p0 >> 9);
  int kk0 = (int)(p0 & 511);

#pragma unroll
  for (int it = 0; it < 8; ++it) {
    int l = it * 256 + tid;
    int pos = l >> 5, c4 = l & 31;
    ushort4 v = *(const ushort4*)(xln + (p0 + pos) * 128 + c4 * 4);
    xl[(c4 * 4 + 0) * 66 + pos] = v.x;
    xl[(c4 * 4 + 1) * 66 + pos] = v.y;
    xl[(c4 * 4 + 2) * 66 + pos] = v.z;
    xl[(c4 * 4 + 3) * 66 + pos] = v.w;
  }

  int tx = tid & 15, ty = tid >> 4;

  for (int h = 0; h < 2; ++h) {
    __syncthreads();
#pragma unroll
    for (int it = 0; it < 8; ++it) {
      int l = it * 256 + tid;
      int k = l >> 4, o4 = l & 15;
      float4 a = *(const float4*)(Wp + k * 128 + h * 64 + o4 * 4);
      ushort4 u;
      u.x = f2bf(a.x); u.y = f2bf(a.y); u.z = f2bf(a.z); u.w = f2bf(a.w);
      *(ushort4*)(w0 + k * 64 + o4 * 4) = u;
      float4 c = *(const float4*)(Wg + k * 128 + h * 64 + o4 * 4);
      ushort4 u2;
      u2.x = f2bf(c.x); u2.y = f2bf(c.y); u2.z = f2bf(c.z); u2.w = f2bf(c.w);
      *(ushort4*)(w1 + k * 64 + o4 * 4) = u2;
    }
    __syncthreads();

    float acc0[4][4] = {{0}};
    float acc1[4][4] = {{0}};
#pragma unroll 8
    for (int k = 0; k < 128; ++k) {
      float a[4];
      ushort2 a0 = *(const ushort2*)(xl + k * 66 + ty * 4);
      ushort2 a1 = *(const ushort2*)(xl + k * 66 + ty * 4 + 2);
      a[0] = bf2f(a0.x); a[1] = bf2f(a0.y); a[2] = bf2f(a1.x); a[3] = bf2f(a1.y);
      ushort4 bv0 = *(const ushort4*)(w0 + k * 64 + tx * 4);
      ushort4 bv1 = *(const ushort4*)(w1 + k * 64 + tx * 4);
      float b0[4] = {bf2f(bv0.x), bf2f(bv0.y), bf2f(bv0.z), bf2f(bv0.w)};
      float b1[4] = {bf2f(bv1.x), bf2f(bv1.y), bf2f(bv1.z), bf2f(bv1.w)};
#pragma unroll
      for (int pp = 0; pp < 4; ++pp) {
#pragma unroll
        for (int oo = 0; oo < 4; ++oo) {
          acc0[pp][oo] = fmaf(a[pp], b0[oo], acc0[pp][oo]);
          acc1[pp][oo] = fmaf(a[pp], b1[oo], acc1[pp][oo]);
        }
      }
    }
    __syncthreads();

    float bp[4], bg[4];
#pragma unroll
    for (int oo = 0; oo < 4; ++oo) {
      bp[oo] = Bp[h * 64 + tx * 4 + oo];
      bg[oo] = Bg[h * 64 + tx * 4 + oo];
    }
#pragma unroll
    for (int pp = 0; pp < 4; ++pp) {
      float mk = mask[p0 + ty * 4 + pp];
#pragma unroll
      for (int oo = 0; oo < 4; ++oo) {
        int o = tx * 4 + oo;
        float val = mk * (acc0[pp][oo] + bp[oo]) * sigm(acc1[pp][oo] + bg[oo]);
        tb[o * 68 + ty * 4 + pp] = f2bf(val);
      }
    }
    __syncthreads();
#pragma unroll
    for (int it = 0; it < 4; ++it) {
      int l = it * 256 + tid;
      int o = l >> 4, j4 = l & 15;
      ushort4 v = *(const ushort4*)(tb + o * 68 + j4 * 4);
      *(ushort4*)(Tout + (size_t)(h * 64 + o) * NN_ + (size_t)i_row * 512 + kk0 + j4 * 4) = v;
    }
  }
}

// ---------------------------------------------------------------------------
// K2 (gate): Gs[p][o] = sigmoid(x @ wgate + bgate), position-major bf16.
// ---------------------------------------------------------------------------
__global__ __launch_bounds__(256) void k2_gate(const u16* __restrict__ xln,
                                               const float* __restrict__ Wg,
                                               const float* __restrict__ Bg,
                                               u16* __restrict__ Gs) {
  __shared__ __align__(16) unsigned char smem[16896 + 32768];
  u16* xl = (u16*)smem;             // [128][66]
  u16* wb = (u16*)(smem + 16896);   // [128][128]

  int tid = threadIdx.x;
  size_t p0 = (size_t)blockIdx.x * 64;

#pragma unroll
  for (int it = 0; it < 8; ++it) {
    int l = it * 256 + tid;
    int pos = l >> 5, c4 = l & 31;
    ushort4 v = *(const ushort4*)(xln + (p0 + pos) * 128 + c4 * 4);
    xl[(c4 * 4 + 0) * 66 + pos] = v.x;
    xl[(c4 * 4 + 1) * 66 + pos] = v.y;
    xl[(c4 * 4 + 2) * 66 + pos] = v.z;
    xl[(c4 * 4 + 3) * 66 + pos] = v.w;
  }
#pragma unroll
  for (int it = 0; it < 16; ++it) {
    int l = it * 256 + tid;
    int k = l >> 5, o4 = l & 31;
    float4 a = *(const float4*)(Wg + k * 128 + o4 * 4);
    ushort4 u;
    u.x = f2bf(a.x); u.y = f2bf(a.y); u.z = f2bf(a.z); u.w = f2bf(a.w);
    *(ushort4*)(wb + k * 128 + o4 * 4) = u;
  }
  __syncthreads();

  int tx = tid & 15, ty = tid >> 4;
  float acc[4][8] = {{0}};
#pragma unroll 8
  for (int k = 0; k < 128; ++k) {
    float a[4];
    ushort2 a0 = *(const ushort2*)(xl + k * 66 + ty * 4);
    ushort2 a1 = *(const ushort2*)(xl + k * 66 + ty * 4 + 2);
    a[0] = bf2f(a0.x); a[1] = bf2f(a0.y); a[2] = bf2f(a1.x); a[3] = bf2f(a1.y);
    ushort4 b0 = *(const ushort4*)(wb + k * 128 + tx * 8);
    ushort4 b1 = *(const ushort4*)(wb + k * 128 + tx * 8 + 4);
    float b[8] = {bf2f(b0.x), bf2f(b0.y), bf2f(b0.z), bf2f(b0.w),
                  bf2f(b1.x), bf2f(b1.y), bf2f(b1.z), bf2f(b1.w)};
#pragma unroll
    for (int pp = 0; pp < 4; ++pp)
#pragma unroll
      for (int oo = 0; oo < 8; ++oo)
        acc[pp][oo] = fmaf(a[pp], b[oo], acc[pp][oo]);
  }
  float bg[8];
#pragma unroll
  for (int oo = 0; oo < 8; ++oo) bg[oo] = Bg[tx * 8 + oo];
#pragma unroll
  for (int pp = 0; pp < 4; ++pp) {
    size_t p = p0 + ty * 4 + pp;
    ushort4 v0, v1;
    v0.x = f2bf(sigm(acc[pp][0] + bg[0]));
    v0.y = f2bf(sigm(acc[pp][1] + bg[1]));
    v0.z = f2bf(sigm(acc[pp][2] + bg[2]));
    v0.w = f2bf(sigm(acc[pp][3] + bg[3]));
    v1.x = f2bf(sigm(acc[pp][4] + bg[4]));
    v1.y = f2bf(sigm(acc[pp][5] + bg[5]));
    v1.z = f2bf(sigm(acc[pp][6] + bg[6]));
    v1.w = f2bf(sigm(acc[pp][7] + bg[7]));
    *(ushort4*)(Gs + p * 128 + tx * 8) = v0;
    *(ushort4*)(Gs + p * 128 + tx * 8 + 4) = v1;
  }
}

// ---------------------------------------------------------------------------
// K3 (MFMA): per-channel NT GEMM Ot[c][i][j] = sum_k Lt[c][i][k]*Rt[c][j][k].
// BM=BN=128, BK=64, 4 waves (2x2), each wave 64x64 = 4x4 frags of 16x16x32.
// global_load_lds(16B) staging, linear LDS dest + XOR-swizzled global source
// (k8' = k8 ^ (row&7)); same XOR on ds_read_b128 -> ~2-way banks (free).
// Epilogue restages C through LDS (band-XOR) for 256B-coalesced dwordx4 stores.
// ---------------------------------------------------------------------------
__global__ __launch_bounds__(256) void k3_einsum_mfma(const u16* __restrict__ Lt,
                                                      const u16* __restrict__ Rt,
                                                      u16* __restrict__ Ot) {
  __shared__ __align__(16) u16 smem[2 * 128 * 64];  // La | Rb ; reused as ob[128][128]
  u16* La = smem;
  u16* Rb = smem + 128 * 64;

  int tid = threadIdx.x;
  int bx = blockIdx.x;
  int c = bx >> 4;                       // 128 channels
  int t = bx & 15;                       // 4x4 tiles of 128
  int i0 = (t >> 2) << 7, j0 = (t & 3) << 7;
  const u16* Lg = Lt + (size_t)c * NN_ + (size_t)i0 * 512;
  const u16* Rg = Rt + (size_t)c * NN_ + (size_t)j0 * 512;

  int l = tid & 63, w = tid >> 6;
  int wr = w >> 1, wc = w & 1;           // wave -> 64x64 quadrant
  int lr = l & 15, lk = l >> 4;          // frag row, k-block-of-8

  f32x4_t acc[4][4];
#pragma unroll
  for (int m = 0; m < 4; ++m)
#pragma unroll
    for (int n = 0; n < 4; ++n) acc[m][n] = (f32x4_t){0.f, 0.f, 0.f, 0.f};

  for (int kt = 0; kt < 512; kt += 64) {
    // stage both 128x64 tiles: 4 issues x 256 threads x 16B each
#pragma unroll
    for (int q = 0; q < 4; ++q) {
      int s = q * 256 + tid;             // linear 16B slot in [0,1024)
      int row = s >> 3;
      int k8 = (s & 7) ^ (row & 7);      // pre-swizzled global source
      const u16* src = Lg + (size_t)row * 512 + kt + k8 * 8;
      gld_lds16(La + s * 8, src);
      const u16* src2 = Rg + (size_t)row * 512 + kt + k8 * 8;
      gld_lds16(Rb + s * 8, src2);
    }
    __syncthreads();

#pragma unroll
    for (int ks = 0; ks < 2; ++ks) {
      int kb = ks * 4 + lk;
      bf16x8_t af[4], bf[4];
#pragma unroll
      for (int m = 0; m < 4; ++m) {
        int row = wr * 64 + m * 16 + lr;
        af[m] = *(const bf16x8_t*)(La + row * 64 + ((kb ^ (row & 7)) * 8));
      }
#pragma unroll
      for (int n = 0; n < 4; ++n) {
        int row = wc * 64 + n * 16 + lr;
        bf[n] = *(const bf16x8_t*)(Rb + row * 64 + ((kb ^ (row & 7)) * 8));
      }
#pragma unroll
      for (int m = 0; m < 4; ++m)
#pragma unroll
        for (int n = 0; n < 4; ++n)
          acc[m][n] = __builtin_amdgcn_mfma_f32_16x16x32_bf16(af[m], bf[n], acc[m][n], 0, 0, 0);
    }
    __syncthreads();
  }

  // epilogue: acc -> ob[128][128] (16-col band XOR by lane k-group), then
  // coalesced dwordx4 stores. ob reuses La|Rb (32 KB exactly).
  u16* ob = smem;
#pragma unroll
  for (int m = 0; m < 4; ++m) {
    int row0 = wr * 64 + m * 16 + lk * 4;
#pragma unroll
    for (int n = 0; n < 4; ++n) {
      int col = (wc * 64 + n * 16 + lr) ^ (lk << 4);
#pragma unroll
      for (int r = 0; r < 4; ++r)
        ob[(row0 + r) * 128 + col] = f2bf(acc[m][n][r]);
    }
  }
  __syncthreads();
#pragma unroll
  for (int it = 0; it < 8; ++it) {
    int s = it * 256 + tid;
    int row = s >> 4, c8 = s & 15;
    int g = (row >> 2) & 3;
    const u16* src = ob + row * 128 + ((c8 * 8) ^ (g << 4));
    *(uint4*)(Ot + (size_t)c * NN_ + (size_t)(i0 + row) * 512 + j0 + c8 * 8) =
        *(const uint4*)src;
  }
}

// ---------------------------------------------------------------------------
// K4: center LN over MID + out = LN(.) @ wout + bout, times sigmoid-gate.
// ---------------------------------------------------------------------------
__global__ __launch_bounds__(256) void k4_out(const u16* __restrict__ Ot,
                                              const u16* __restrict__ Gs,
                                              const float* __restrict__ gc,
                                              const float* __restrict__ bc,
                                              const float* __restrict__ wout,
                                              const float* __restrict__ bout,
                                              float* __restrict__ out) {
  __shared__ __align__(16) unsigned char smem[34816 + 32768];
  float* xm = (float*)smem;               // [128][68] f32
  u16* ot = (u16*)(smem + 34816);         // [128][64] bf16
  u16* wb = (u16*)(smem + 34816);         // [128][128] bf16 (after LN phase)

  int tid = threadIdx.x;
  size_t p0 = (size_t)blockIdx.x * 64;
  int i_row = (int)(p0 >> 9);
  int j0 = (int)(p0 & 511);

#pragma unroll
  for (int it = 0; it < 8; ++it) {
    int l = it * 256 + tid;
    int cc = l >> 4, j4 = l & 15;
    ushort4 v = *(const ushort4*)(Ot + (size_t)cc * NN_ + (size_t)i_row * 512 + j0 + j4 * 4);
    *(ushort4*)(ot + cc * 64 + j4 * 4) = v;
  }
  __syncthreads();

  {
    int pos = tid >> 2, q = tid & 3;
    float s = 0.0f, ss = 0.0f;
    float vals[32];
#pragma unroll
    for (int m = 0; m < 32; ++m) {
      float v = bf2f(ot[(q * 32 + m) * 64 + pos]);
      vals[m] = v;
      s += v;
      ss += v * v;
    }
    s += __shfl_xor(s, 1); ss += __shfl_xor(ss, 1);
    s += __shfl_xor(s, 2); ss += __shfl_xor(ss, 2);
    float mu = s * (1.0f / 128.0f);
    float rstd = rsqrtf(ss * (1.0f / 128.0f) - mu * mu + 1e-5f);
#pragma unroll
    for (int m = 0; m < 32; ++m) {
      int cc = q * 32 + m;
      xm[cc * 68 + pos] = (vals[m] - mu) * rstd * gc[cc] + bc[cc];
    }
  }
  __syncthreads();

#pragma unroll
  for (int it = 0; it < 16; ++it) {
    int l = it * 256 + tid;
    int k = l >> 5, o4 = l & 31;
    float4 a = *(const float4*)(wout + k * 128 + o4 * 4);
    ushort4 u;
    u.x = f2bf(a.x); u.y = f2bf(a.y); u.z = f2bf(a.z); u.w = f2bf(a.w);
    *(ushort4*)(wb + k * 128 + o4 * 4) = u;
  }
  __syncthreads();

  int tx = tid & 15, ty = tid >> 4;
  float acc[4][8] = {{0}};
#pragma unroll 8
  for (int k = 0; k < 128; ++k) {
    float av[4];
    *(float4*)av = *(const float4*)(xm + k * 68 + ty * 4);
    ushort4 b0 = *(const ushort4*)(wb + k * 128 + tx * 8);
    ushort4 b1 = *(const ushort4*)(wb + k * 128 + tx * 8 + 4);
    float b[8] = {bf2f(b0.x), bf2f(b0.y), bf2f(b0.z), bf2f(b0.w),
                  bf2f(b1.x), bf2f(b1.y), bf2f(b1.z), bf2f(b1.w)};
#pragma unroll
    for (int pp = 0; pp < 4; ++pp)
#pragma unroll
      for (int oo = 0; oo < 8; ++oo)
        acc[pp][oo] = fmaf(av[pp], b[oo], acc[pp][oo]);
  }
  float bo[8];
#pragma unroll
  for (int oo = 0; oo < 8; ++oo) bo[oo] = bout[tx * 8 + oo];
#pragma unroll
  for (int pp = 0; pp < 4; ++pp) {
    size_t p = p0 + ty * 4 + pp;
    ushort4 g0 = *(const ushort4*)(Gs + p * 128 + tx * 8);
    ushort4 g1 = *(const ushort4*)(Gs + p * 128 + tx * 8 + 4);
    float y[8];
    y[0] = (acc[pp][0] + bo[0]) * bf2f(g0.x);
    y[1] = (acc[pp][1] + bo[1]) * bf2f(g0.y);
    y[2] = (acc[pp][2] + bo[2]) * bf2f(g0.z);
    y[3] = (acc[pp][3] + bo[3]) * bf2f(g0.w);
    y[4] = (acc[pp][4] + bo[4]) * bf2f(g1.x);
    y[5] = (acc[pp][5] + bo[5]) * bf2f(g1.y);
    y[6] = (acc[pp][6] + bo[6]) * bf2f(g1.z);
    y[7] = (acc[pp][7] + bo[7]) * bf2f(g1.w);
    float4 f0 = {y[0], y[1], y[2], y[3]};
    float4 f1 = {y[4], y[5], y[6], y[7]};
    *(float4*)(out + p * 128 + tx * 8) = f0;
    *(float4*)(out + p * 128 + tx * 8 + 4) = f1;
  }
}

// ---------------------------------------------------------------------------
extern "C" void kernel_launch(void* const* d_in, const int* in_sizes, int n_in,
                              void* d_out, int out_size, void* d_ws, size_t ws_size,
                              hipStream_t stream) {
  const float* act    = (const float*)d_in[0];
  const float* mask   = (const float*)d_in[1];
  const float* ln_in_g = (const float*)d_in[2];
  const float* ln_in_b = (const float*)d_in[3];
  const float* wl     = (const float*)d_in[4];
  const float* bl     = (const float*)d_in[5];
  const float* wr     = (const float*)d_in[6];
  const float* br     = (const float*)d_in[7];
  const float* wgl    = (const float*)d_in[8];
  const float* bgl    = (const float*)d_in[9];
  const float* wgr    = (const float*)d_in[10];
  const float* bgr    = (const float*)d_in[11];
  const float* wgate  = (const float*)d_in[12];
  const float* bgate  = (const float*)d_in[13];
  const float* ln_c_g = (const float*)d_in[14];
  const float* ln_c_b = (const float*)d_in[15];
  const float* wout   = (const float*)d_in[16];
  const float* bout   = (const float*)d_in[17];
  float* out = (float*)d_out;

  char* ws = (char*)d_ws;
  const size_t SEG = 1ull << 26;  // 64 MiB per bf16 [128][512][512] buffer
  u16* Lt  = (u16*)(ws);
  u16* Rt  = (u16*)(ws + 1 * SEG);
  u16* Gs  = (u16*)(ws + 2 * SEG);
  u16* Ot  = (u16*)(ws + 3 * SEG);
  u16* xln = Ot;  // alias: xln lifetime [K1,K2], Ot lifetime [K3,K4]

  k1_ln<<<dim3(65536), dim3(256), 0, stream>>>(act, ln_in_g, ln_in_b, xln);
  k2_pair<<<dim3(4096), dim3(256), 0, stream>>>(xln, mask, wl, bl, wgl, bgl, Lt);
  k2_pair<<<dim3(4096), dim3(256), 0, stream>>>(xln, mask, wr, br, wgr, bgr, Rt);
  k2_gate<<<dim3(4096), dim3(256), 0, stream>>>(xln, wgate, bgate, Gs);
  k3_einsum_mfma<<<dim3(2048), dim3(256), 0, stream>>>(Lt, Rt, Ot);
  k4_out<<<dim3(4096), dim3(256), 0, stream>>>(Ot, Gs, ln_c_g, ln_c_b, wout, bout, out);
}

// Round 4
// 406.780 us; speedup vs baseline: 3.2397x; 2.4280x over previous
//
#include <hip/hip_runtime.h>

#define NPOS 512
#define NN_ (512 * 512)

typedef unsigned short u16;
typedef __attribute__((ext_vector_type(8))) short bf16x8_t;  // 8 bf16 in 4 VGPRs
typedef __attribute__((ext_vector_type(4))) float f32x4_t;   // MFMA acc

__device__ __forceinline__ float bf2f(u16 u) {
  union { unsigned int i; float f; } v;
  v.i = ((unsigned int)u) << 16;
  return v.f;
}
__device__ __forceinline__ u16 f2bf(float f) {
  unsigned int u = __float_as_uint(f);
  unsigned int r = (u + 0x7fffu + ((u >> 16) & 1u)) >> 16;
  return (u16)r;
}
__device__ __forceinline__ float sigm(float x) { return 1.0f / (1.0f + __expf(-x)); }

// async global->LDS, 16B per lane (dest must be wave-linear: base + lane*16).
__device__ __forceinline__ void gld_lds16(u16* lds, const u16* g) {
  __builtin_amdgcn_global_load_lds(
      (const __attribute__((address_space(1))) unsigned int*)g,
      (__attribute__((address_space(3))) unsigned int*)lds, 16, 0, 0);
}

// ---------------------------------------------------------------------------
// K0: pre-transpose 5 projection weights to bf16 Wt[o][k] (k contiguous).
// Output lives in the tail of d_out (dead until k4 rewrites everything).
// 40 blocks = 5 weights x 8 o-bands of 16.
// ---------------------------------------------------------------------------
__global__ __launch_bounds__(256) void k0_wt(const float* __restrict__ wl,
                                             const float* __restrict__ wgl,
                                             const float* __restrict__ wr,
                                             const float* __restrict__ wgr,
                                             const float* __restrict__ wgate,
                                             u16* __restrict__ wtbase) {
  int b = blockIdx.x;
  int wi = b >> 3;
  int o0 = (b & 7) * 16;
  const float* W = wi == 0 ? wl : wi == 1 ? wgl : wi == 2 ? wr : wi == 3 ? wgr : wgate;
  u16* dst = wtbase + wi * 16384;
  int t = threadIdx.x;
  int o = o0 + (t >> 4);
  int k0 = (t & 15) * 8;
  float v[8];
#pragma unroll
  for (int i = 0; i < 8; ++i) v[i] = W[(k0 + i) * 128 + o];
  ushort4 a, b4;
  a.x = f2bf(v[0]); a.y = f2bf(v[1]); a.z = f2bf(v[2]); a.w = f2bf(v[3]);
  b4.x = f2bf(v[4]); b4.y = f2bf(v[5]); b4.z = f2bf(v[6]); b4.w = f2bf(v[7]);
  *(ushort4*)(dst + o * 128 + k0) = a;
  *(ushort4*)(dst + o * 128 + k0 + 4) = b4;
}

// ---------------------------------------------------------------------------
// K1: input LayerNorm over C=128. One wave (64 lanes) per position, 2 vals/lane.
// ---------------------------------------------------------------------------
__global__ __launch_bounds__(256) void k1_ln(const float* __restrict__ act,
                                             const float* __restrict__ g,
                                             const float* __restrict__ b,
                                             u16* __restrict__ xln) {
  int wave = threadIdx.x >> 6, lane = threadIdx.x & 63;
  size_t p = (size_t)blockIdx.x * 4 + wave;
  const float* row = act + p * 128;
  float2 v = *(const float2*)(row + lane * 2);
  float s = v.x + v.y;
  float ss = v.x * v.x + v.y * v.y;
#pragma unroll
  for (int m = 32; m; m >>= 1) {
    s += __shfl_xor(s, m);
    ss += __shfl_xor(ss, m);
  }
  float mu = s * (1.0f / 128.0f);
  float rstd = rsqrtf(ss * (1.0f / 128.0f) - mu * mu + 1e-5f);
  float y0 = (v.x - mu) * rstd * g[lane * 2] + b[lane * 2];
  float y1 = (v.y - mu) * rstd * g[lane * 2 + 1] + b[lane * 2 + 1];
  ushort2 o;
  o.x = f2bf(y0);
  o.y = f2bf(y1);
  *(ushort2*)(xln + p * 128 + lane * 2) = o;
}

// ---------------------------------------------------------------------------
// K2_all (MFMA): fused 5-GEMM projection kernel. BM=128 positions, K=128.
// 512 threads = 8 waves, octant (wr in 0..3 -> 32 rows, wc in 0..1 -> 64 cols).
// Phases: L (wl,wgl->Lt), R (wr,wgr->Rt), G (wgate->Gs).
// xs and weights staged via gld_lds16 with both-sides XOR swizzle (K3 pattern).
// L/R epilogue: mask*(proj+b)*sigm(gate+b), transpose via pitch-136 LDS ob,
// 16B-coalesced store to Tout[o][i_row][j0..j0+128).
// ---------------------------------------------------------------------------
__global__ __launch_bounds__(512, 2) void k2_all(
    const u16* __restrict__ xln, const float* __restrict__ mask,
    const u16* __restrict__ wtbase,
    const float* __restrict__ bl, const float* __restrict__ bgl,
    const float* __restrict__ br, const float* __restrict__ bgr,
    const float* __restrict__ bgate,
    u16* __restrict__ Lt, u16* __restrict__ Rt, u16* __restrict__ Gs) {
  __shared__ __align__(16) u16 smem[3 * 128 * 128];  // 96 KB
  u16* xs = smem;            // [128 p][128 k] swizzled
  u16* wp = smem + 16384;    // [128 o][128 k] swizzled
  u16* wg = smem + 32768;    // [128 o][128 k] swizzled
  u16* ob = wp;              // epilogue [128 o][136] overlay (34.8 KB)

  int tid = threadIdx.x;
  int l = tid & 63, w = tid >> 6;
  int wr = w >> 1, wc = w & 1;
  int lr = l & 15, lk = l >> 4;
  size_t p0 = (size_t)blockIdx.x * 128;
  int i_row = (int)(p0 >> 9);
  int j0 = (int)(p0 & 511);

  // stage xs (2048 16B slots)
#pragma unroll
  for (int q = 0; q < 4; ++q) {
    int s = q * 512 + tid;
    int row = s >> 4;
    int j = (s & 15) ^ (row & 7);
    gld_lds16(xs + s * 8, xln + (p0 + row) * 128 + j * 8);
  }

  for (int ph = 0; ph < 3; ++ph) {
    const u16* wtp = wtbase + (ph * 2) * 16384;
    const u16* wtg = wtbase + (ph * 2 + 1) * 16384;
    const float* Bp = ph == 0 ? bl : ph == 1 ? br : bgate;
    const float* Bg = ph == 0 ? bgl : bgr;
    u16* Tdst = ph == 0 ? Lt : Rt;

    if (ph) __syncthreads();  // prior epilogue's ob reads complete
#pragma unroll
    for (int q = 0; q < 4; ++q) {
      int s = q * 512 + tid;
      int row = s >> 4;
      int j = (s & 15) ^ (row & 7);
      gld_lds16(wp + s * 8, wtp + row * 128 + j * 8);
    }
    if (ph < 2) {
#pragma unroll
      for (int q = 0; q < 4; ++q) {
        int s = q * 512 + tid;
        int row = s >> 4;
        int j = (s & 15) ^ (row & 7);
        gld_lds16(wg + s * 8, wtg + row * 128 + j * 8);
      }
    }
    __syncthreads();  // drains vmcnt (incl. xs on first phase)

    f32x4_t ap[2][4], ag[2][4];
#pragma unroll
    for (int m = 0; m < 2; ++m)
#pragma unroll
      for (int n = 0; n < 4; ++n) {
        ap[m][n] = (f32x4_t){0.f, 0.f, 0.f, 0.f};
        ag[m][n] = (f32x4_t){0.f, 0.f, 0.f, 0.f};
      }

#pragma unroll
    for (int kt = 0; kt < 4; ++kt) {
      int kb = kt * 4 + lk;
      bf16x8_t af[2], bp_[4], bg_[4];
#pragma unroll
      for (int m = 0; m < 2; ++m) {
        int row = wr * 32 + m * 16 + lr;
        af[m] = *(const bf16x8_t*)(xs + row * 128 + ((kb ^ (row & 7)) * 8));
      }
#pragma unroll
      for (int n = 0; n < 4; ++n) {
        int orow = wc * 64 + n * 16 + lr;
        bp_[n] = *(const bf16x8_t*)(wp + orow * 128 + ((kb ^ (orow & 7)) * 8));
      }
      if (ph < 2) {
#pragma unroll
        for (int n = 0; n < 4; ++n) {
          int orow = wc * 64 + n * 16 + lr;
          bg_[n] = *(const bf16x8_t*)(wg + orow * 128 + ((kb ^ (orow & 7)) * 8));
        }
      }
#pragma unroll
      for (int m = 0; m < 2; ++m)
#pragma unroll
        for (int n = 0; n < 4; ++n)
          ap[m][n] = __builtin_amdgcn_mfma_f32_16x16x32_bf16(af[m], bp_[n], ap[m][n], 0, 0, 0);
      if (ph < 2) {
#pragma unroll
        for (int m = 0; m < 2; ++m)
#pragma unroll
          for (int n = 0; n < 4; ++n)
            ag[m][n] = __builtin_amdgcn_mfma_f32_16x16x32_bf16(af[m], bg_[n], ag[m][n], 0, 0, 0);
      }
    }
    __syncthreads();  // wp/wg reads done before ob overwrite / next stage

    if (ph < 2) {
      float bpv[4], bgv[4];
#pragma unroll
      for (int n = 0; n < 4; ++n) {
        int o = wc * 64 + n * 16 + lr;
        bpv[n] = Bp[o];
        bgv[n] = Bg[o];
      }
#pragma unroll
      for (int m = 0; m < 2; ++m) {
        int p4 = wr * 32 + m * 16 + lk * 4;
        float4 mk = *(const float4*)(mask + p0 + p4);
#pragma unroll
        for (int n = 0; n < 4; ++n) {
          int o = wc * 64 + n * 16 + lr;
          ushort4 v;
          v.x = f2bf(mk.x * (ap[m][n][0] + bpv[n]) * sigm(ag[m][n][0] + bgv[n]));
          v.y = f2bf(mk.y * (ap[m][n][1] + bpv[n]) * sigm(ag[m][n][1] + bgv[n]));
          v.z = f2bf(mk.z * (ap[m][n][2] + bpv[n]) * sigm(ag[m][n][2] + bgv[n]));
          v.w = f2bf(mk.w * (ap[m][n][3] + bpv[n]) * sigm(ag[m][n][3] + bgv[n]));
          *(ushort4*)(ob + o * 136 + p4) = v;
        }
      }
      __syncthreads();
#pragma unroll
      for (int it = 0; it < 4; ++it) {
        int s = it * 512 + tid;
        int o = s >> 4, c8 = s & 15;
        *(uint4*)(Tdst + (size_t)o * NN_ + (size_t)i_row * 512 + j0 + c8 * 8) =
            *(const uint4*)(ob + o * 136 + c8 * 8);
      }
    } else {
      float bpv[4];
#pragma unroll
      for (int n = 0; n < 4; ++n) bpv[n] = Bp[wc * 64 + n * 16 + lr];
#pragma unroll
      for (int m = 0; m < 2; ++m) {
        int p4 = wr * 32 + m * 16 + lk * 4;
#pragma unroll
        for (int n = 0; n < 4; ++n) {
          int o = wc * 64 + n * 16 + lr;
#pragma unroll
          for (int r = 0; r < 4; ++r)
            Gs[(p0 + p4 + r) * 128 + o] = f2bf(sigm(ap[m][n][r] + bpv[n]));
        }
      }
    }
  }
}

// ---------------------------------------------------------------------------
// K3 (MFMA): per-channel NT GEMM Ot[c][i][j] = sum_k Lt[c][i][k]*Rt[c][j][k].
// (verified in R3 — unchanged)
// ---------------------------------------------------------------------------
__global__ __launch_bounds__(256) void k3_einsum_mfma(const u16* __restrict__ Lt,
                                                      const u16* __restrict__ Rt,
                                                      u16* __restrict__ Ot) {
  __shared__ __align__(16) u16 smem[2 * 128 * 64];
  u16* La = smem;
  u16* Rb = smem + 128 * 64;

  int tid = threadIdx.x;
  int bx = blockIdx.x;
  int c = bx >> 4;
  int t = bx & 15;
  int i0 = (t >> 2) << 7, j0 = (t & 3) << 7;
  const u16* Lg = Lt + (size_t)c * NN_ + (size_t)i0 * 512;
  const u16* Rg = Rt + (size_t)c * NN_ + (size_t)j0 * 512;

  int l = tid & 63, w = tid >> 6;
  int wr = w >> 1, wc = w & 1;
  int lr = l & 15, lk = l >> 4;

  f32x4_t acc[4][4];
#pragma unroll
  for (int m = 0; m < 4; ++m)
#pragma unroll
    for (int n = 0; n < 4; ++n) acc[m][n] = (f32x4_t){0.f, 0.f, 0.f, 0.f};

  for (int kt = 0; kt < 512; kt += 64) {
#pragma unroll
    for (int q = 0; q < 4; ++q) {
      int s = q * 256 + tid;
      int row = s >> 3;
      int k8 = (s & 7) ^ (row & 7);
      gld_lds16(La + s * 8, Lg + (size_t)row * 512 + kt + k8 * 8);
      gld_lds16(Rb + s * 8, Rg + (size_t)row * 512 + kt + k8 * 8);
    }
    __syncthreads();

#pragma unroll
    for (int ks = 0; ks < 2; ++ks) {
      int kb = ks * 4 + lk;
      bf16x8_t af[4], bf[4];
#pragma unroll
      for (int m = 0; m < 4; ++m) {
        int row = wr * 64 + m * 16 + lr;
        af[m] = *(const bf16x8_t*)(La + row * 64 + ((kb ^ (row & 7)) * 8));
      }
#pragma unroll
      for (int n = 0; n < 4; ++n) {
        int row = wc * 64 + n * 16 + lr;
        bf[n] = *(const bf16x8_t*)(Rb + row * 64 + ((kb ^ (row & 7)) * 8));
      }
#pragma unroll
      for (int m = 0; m < 4; ++m)
#pragma unroll
        for (int n = 0; n < 4; ++n)
          acc[m][n] = __builtin_amdgcn_mfma_f32_16x16x32_bf16(af[m], bf[n], acc[m][n], 0, 0, 0);
    }
    __syncthreads();
  }

  u16* ob = smem;
#pragma unroll
  for (int m = 0; m < 4; ++m) {
    int row0 = wr * 64 + m * 16 + lk * 4;
#pragma unroll
    for (int n = 0; n < 4; ++n) {
      int col = (wc * 64 + n * 16 + lr) ^ (lk << 4);
#pragma unroll
      for (int r = 0; r < 4; ++r)
        ob[(row0 + r) * 128 + col] = f2bf(acc[m][n][r]);
    }
  }
  __syncthreads();
#pragma unroll
  for (int it = 0; it < 8; ++it) {
    int s = it * 256 + tid;
    int row = s >> 4, c8 = s & 15;
    int g = (row >> 2) & 3;
    const u16* src = ob + row * 128 + ((c8 * 8) ^ (g << 4));
    *(uint4*)(Ot + (size_t)c * NN_ + (size_t)(i0 + row) * 512 + j0 + c8 * 8) =
        *(const uint4*)src;
  }
}

// ---------------------------------------------------------------------------
// K4: center LN over MID + out = LN(.) @ wout + bout, times sigmoid-gate.
// ---------------------------------------------------------------------------
__global__ __launch_bounds__(256) void k4_out(const u16* __restrict__ Ot,
                                              const u16* __restrict__ Gs,
                                              const float* __restrict__ gc,
                                              const float* __restrict__ bc,
                                              const float* __restrict__ wout,
                                              const float* __restrict__ bout,
                                              float* __restrict__ out) {
  __shared__ __align__(16) unsigned char smem[34816 + 32768];
  float* xm = (float*)smem;               // [128][68] f32
  u16* ot = (u16*)(smem + 34816);         // [128][64] bf16
  u16* wb = (u16*)(smem + 34816);         // [128][128] bf16 (after LN phase)

  int tid = threadIdx.x;
  size_t p0 = (size_t)blockIdx.x * 64;
  int i_row = (int)(p0 >> 9);
  int j0 = (int)(p0 & 511);

#pragma unroll
  for (int it = 0; it < 8; ++it) {
    int l = it * 256 + tid;
    int cc = l >> 4, j4 = l & 15;
    ushort4 v = *(const ushort4*)(Ot + (size_t)cc * NN_ + (size_t)i_row * 512 + j0 + j4 * 4);
    *(ushort4*)(ot + cc * 64 + j4 * 4) = v;
  }
  __syncthreads();

  {
    int pos = tid >> 2, q = tid & 3;
    float s = 0.0f, ss = 0.0f;
    float vals[32];
#pragma unroll
    for (int m = 0; m < 32; ++m) {
      float v = bf2f(ot[(q * 32 + m) * 64 + pos]);
      vals[m] = v;
      s += v;
      ss += v * v;
    }
    s += __shfl_xor(s, 1); ss += __shfl_xor(ss, 1);
    s += __shfl_xor(s, 2); ss += __shfl_xor(ss, 2);
    float mu = s * (1.0f / 128.0f);
    float rstd = rsqrtf(ss * (1.0f / 128.0f) - mu * mu + 1e-5f);
#pragma unroll
    for (int m = 0; m < 32; ++m) {
      int cc = q * 32 + m;
      xm[cc * 68 + pos] = (vals[m] - mu) * rstd * gc[cc] + bc[cc];
    }
  }
  __syncthreads();

#pragma unroll
  for (int it = 0; it < 16; ++it) {
    int l = it * 256 + tid;
    int k = l >> 5, o4 = l & 31;
    float4 a = *(const float4*)(wout + k * 128 + o4 * 4);
    ushort4 u;
    u.x = f2bf(a.x); u.y = f2bf(a.y); u.z = f2bf(a.z); u.w = f2bf(a.w);
    *(ushort4*)(wb + k * 128 + o4 * 4) = u;
  }
  __syncthreads();

  int tx = tid & 15, ty = tid >> 4;
  float acc[4][8] = {{0}};
#pragma unroll 8
  for (int k = 0; k < 128; ++k) {
    float av[4];
    *(float4*)av = *(const float4*)(xm + k * 68 + ty * 4);
    ushort4 b0 = *(const ushort4*)(wb + k * 128 + tx * 8);
    ushort4 b1 = *(const ushort4*)(wb + k * 128 + tx * 8 + 4);
    float b[8] = {bf2f(b0.x), bf2f(b0.y), bf2f(b0.z), bf2f(b0.w),
                  bf2f(b1.x), bf2f(b1.y), bf2f(b1.z), bf2f(b1.w)};
#pragma unroll
    for (int pp = 0; pp < 4; ++pp)
#pragma unroll
      for (int oo = 0; oo < 8; ++oo)
        acc[pp][oo] = fmaf(av[pp], b[oo], acc[pp][oo]);
  }
  float bo[8];
#pragma unroll
  for (int oo = 0; oo < 8; ++oo) bo[oo] = bout[tx * 8 + oo];
#pragma unroll
  for (int pp = 0; pp < 4; ++pp) {
    size_t p = p0 + ty * 4 + pp;
    ushort4 g0 = *(const ushort4*)(Gs + p * 128 + tx * 8);
    ushort4 g1 = *(const ushort4*)(Gs + p * 128 + tx * 8 + 4);
    float y[8];
    y[0] = (acc[pp][0] + bo[0]) * bf2f(g0.x);
    y[1] = (acc[pp][1] + bo[1]) * bf2f(g0.y);
    y[2] = (acc[pp][2] + bo[2]) * bf2f(g0.z);
    y[3] = (acc[pp][3] + bo[3]) * bf2f(g0.w);
    y[4] = (acc[pp][4] + bo[4]) * bf2f(g1.x);
    y[5] = (acc[pp][5] + bo[5]) * bf2f(g1.y);
    y[6] = (acc[pp][6] + bo[6]) * bf2f(g1.z);
    y[7] = (acc[pp][7] + bo[7]) * bf2f(g1.w);
    float4 f0 = {y[0], y[1], y[2], y[3]};
    float4 f1 = {y[4], y[5], y[6], y[7]};
    *(float4*)(out + p * 128 + tx * 8) = f0;
    *(float4*)(out + p * 128 + tx * 8 + 4) = f1;
  }
}

// ---------------------------------------------------------------------------
extern "C" void kernel_launch(void* const* d_in, const int* in_sizes, int n_in,
                              void* d_out, int out_size, void* d_ws, size_t ws_size,
                              hipStream_t stream) {
  const float* act    = (const float*)d_in[0];
  const float* mask   = (const float*)d_in[1];
  const float* ln_in_g = (const float*)d_in[2];
  const float* ln_in_b = (const float*)d_in[3];
  const float* wl     = (const float*)d_in[4];
  const float* bl     = (const float*)d_in[5];
  const float* wr     = (const float*)d_in[6];
  const float* br     = (const float*)d_in[7];
  const float* wgl    = (const float*)d_in[8];
  const float* bgl    = (const float*)d_in[9];
  const float* wgr    = (const float*)d_in[10];
  const float* bgr    = (const float*)d_in[11];
  const float* wgate  = (const float*)d_in[12];
  const float* bgate  = (const float*)d_in[13];
  const float* ln_c_g = (const float*)d_in[14];
  const float* ln_c_b = (const float*)d_in[15];
  const float* wout   = (const float*)d_in[16];
  const float* bout   = (const float*)d_in[17];
  float* out = (float*)d_out;

  char* ws = (char*)d_ws;
  const size_t SEG = 1ull << 26;  // 64 MiB per bf16 [128][512][512] buffer
  u16* Lt  = (u16*)(ws);
  u16* Rt  = (u16*)(ws + 1 * SEG);
  u16* Gs  = (u16*)(ws + 2 * SEG);
  u16* Ot  = (u16*)(ws + 3 * SEG);
  u16* xln = Ot;  // alias: xln lifetime [K1,K2], Ot lifetime [K3,K4]

  // Wt scratch in the tail of d_out (128 MB); dead before k4 rewrites out.
  u16* wtbase = (u16*)((char*)d_out + (size_t)out_size * 4 - 5 * 32768);

  k0_wt<<<dim3(40), dim3(256), 0, stream>>>(wl, wgl, wr, wgr, wgate, wtbase);
  k1_ln<<<dim3(65536), dim3(256), 0, stream>>>(act, ln_in_g, ln_in_b, xln);
  k2_all<<<dim3(2048), dim3(512), 0, stream>>>(xln, mask, wtbase, bl, bgl, br, bgr,
                                               bgate, Lt, Rt, Gs);
  k3_einsum_mfma<<<dim3(2048), dim3(256), 0, stream>>>(Lt, Rt, Ot);
  k4_out<<<dim3(4096), dim3(256), 0, stream>>>(Ot, Gs, ln_c_g, ln_c_b, wout, bout, out);
}

// Round 5
// 330.329 us; speedup vs baseline: 3.9896x; 1.2314x over previous
//
#include <hip/hip_runtime.h>

#define NPOS 512
#define NN_ (512 * 512)

typedef unsigned short u16;
typedef __attribute__((ext_vector_type(8))) short bf16x8_t;  // 8 bf16 in 4 VGPRs
typedef __attribute__((ext_vector_type(4))) float f32x4_t;   // MFMA acc

__device__ __forceinline__ float bf2f(u16 u) {
  union { unsigned int i; float f; } v;
  v.i = ((unsigned int)u) << 16;
  return v.f;
}
__device__ __forceinline__ u16 f2bf(float f) {
  unsigned int u = __float_as_uint(f);
  unsigned int r = (u + 0x7fffu + ((u >> 16) & 1u)) >> 16;
  return (u16)r;
}
__device__ __forceinline__ float sigm(float x) { return 1.0f / (1.0f + __expf(-x)); }

// async global->LDS, 16B per lane (dest must be wave-linear: base + lane*16).
__device__ __forceinline__ void gld_lds16(u16* lds, const u16* g) {
  __builtin_amdgcn_global_load_lds(
      (const __attribute__((address_space(1))) unsigned int*)g,
      (__attribute__((address_space(3))) unsigned int*)lds, 16, 0, 0);
}

// ---------------------------------------------------------------------------
// K0: pre-transpose 5 projection weights to bf16 Wt[o][k] (k contiguous).
// Output lives in the tail of d_out (read only by k2_all; k4 rewrites out later).
// ---------------------------------------------------------------------------
__global__ __launch_bounds__(256) void k0_wt(const float* __restrict__ wl,
                                             const float* __restrict__ wgl,
                                             const float* __restrict__ wr,
                                             const float* __restrict__ wgr,
                                             const float* __restrict__ wgate,
                                             u16* __restrict__ wtbase) {
  int b = blockIdx.x;
  int wi = b >> 3;
  int o0 = (b & 7) * 16;
  const float* W = wi == 0 ? wl : wi == 1 ? wgl : wi == 2 ? wr : wi == 3 ? wgr : wgate;
  u16* dst = wtbase + wi * 16384;
  int t = threadIdx.x;
  int o = o0 + (t >> 4);
  int k0 = (t & 15) * 8;
  float v[8];
#pragma unroll
  for (int i = 0; i < 8; ++i) v[i] = W[(k0 + i) * 128 + o];
  ushort4 a, b4;
  a.x = f2bf(v[0]); a.y = f2bf(v[1]); a.z = f2bf(v[2]); a.w = f2bf(v[3]);
  b4.x = f2bf(v[4]); b4.y = f2bf(v[5]); b4.z = f2bf(v[6]); b4.w = f2bf(v[7]);
  *(ushort4*)(dst + o * 128 + k0) = a;
  *(ushort4*)(dst + o * 128 + k0 + 4) = b4;
}

// ---------------------------------------------------------------------------
// K0b: transpose wout -> bf16 Wt6[o][k]. Runs AFTER k3; output goes into the
// (now dead) Lt region of the workspace, read only by k4.
// ---------------------------------------------------------------------------
__global__ __launch_bounds__(256) void k0b(const float* __restrict__ wout,
                                           u16* __restrict__ Wt6) {
  int o = blockIdx.x * 16 + (threadIdx.x >> 4);
  int k0 = (threadIdx.x & 15) * 8;
  float v[8];
#pragma unroll
  for (int i = 0; i < 8; ++i) v[i] = wout[(k0 + i) * 128 + o];
  ushort4 a, b4;
  a.x = f2bf(v[0]); a.y = f2bf(v[1]); a.z = f2bf(v[2]); a.w = f2bf(v[3]);
  b4.x = f2bf(v[4]); b4.y = f2bf(v[5]); b4.z = f2bf(v[6]); b4.w = f2bf(v[7]);
  *(ushort4*)(Wt6 + o * 128 + k0) = a;
  *(ushort4*)(Wt6 + o * 128 + k0 + 4) = b4;
}

// ---------------------------------------------------------------------------
// K1: input LayerNorm over C=128. One wave (64 lanes) per position, 2 vals/lane.
// ---------------------------------------------------------------------------
__global__ __launch_bounds__(256) void k1_ln(const float* __restrict__ act,
                                             const float* __restrict__ g,
                                             const float* __restrict__ b,
                                             u16* __restrict__ xln) {
  int wave = threadIdx.x >> 6, lane = threadIdx.x & 63;
  size_t p = (size_t)blockIdx.x * 4 + wave;
  const float* row = act + p * 128;
  float2 v = *(const float2*)(row + lane * 2);
  float s = v.x + v.y;
  float ss = v.x * v.x + v.y * v.y;
#pragma unroll
  for (int m = 32; m; m >>= 1) {
    s += __shfl_xor(s, m);
    ss += __shfl_xor(ss, m);
  }
  float mu = s * (1.0f / 128.0f);
  float rstd = rsqrtf(ss * (1.0f / 128.0f) - mu * mu + 1e-5f);
  float y0 = (v.x - mu) * rstd * g[lane * 2] + b[lane * 2];
  float y1 = (v.y - mu) * rstd * g[lane * 2 + 1] + b[lane * 2 + 1];
  ushort2 o;
  o.x = f2bf(y0);
  o.y = f2bf(y1);
  *(ushort2*)(xln + p * 128 + lane * 2) = o;
}

// ---------------------------------------------------------------------------
// K2_all (MFMA): fused 5-GEMM projection kernel (verified R4 — unchanged).
// ---------------------------------------------------------------------------
__global__ __launch_bounds__(512, 2) void k2_all(
    const u16* __restrict__ xln, const float* __restrict__ mask,
    const u16* __restrict__ wtbase,
    const float* __restrict__ bl, const float* __restrict__ bgl,
    const float* __restrict__ br, const float* __restrict__ bgr,
    const float* __restrict__ bgate,
    u16* __restrict__ Lt, u16* __restrict__ Rt, u16* __restrict__ Gs) {
  __shared__ __align__(16) u16 smem[3 * 128 * 128];  // 96 KB
  u16* xs = smem;            // [128 p][128 k] swizzled
  u16* wp = smem + 16384;    // [128 o][128 k] swizzled
  u16* wg = smem + 32768;    // [128 o][128 k] swizzled
  u16* ob = wp;              // epilogue [128 o][136] overlay

  int tid = threadIdx.x;
  int l = tid & 63, w = tid >> 6;
  int wr = w >> 1, wc = w & 1;
  int lr = l & 15, lk = l >> 4;
  size_t p0 = (size_t)blockIdx.x * 128;
  int i_row = (int)(p0 >> 9);
  int j0 = (int)(p0 & 511);

#pragma unroll
  for (int q = 0; q < 4; ++q) {
    int s = q * 512 + tid;
    int row = s >> 4;
    int j = (s & 15) ^ (row & 7);
    gld_lds16(xs + s * 8, xln + (p0 + row) * 128 + j * 8);
  }

  for (int ph = 0; ph < 3; ++ph) {
    const u16* wtp = wtbase + (ph * 2) * 16384;
    const u16* wtg = wtbase + (ph * 2 + 1) * 16384;
    const float* Bp = ph == 0 ? bl : ph == 1 ? br : bgate;
    const float* Bg = ph == 0 ? bgl : bgr;
    u16* Tdst = ph == 0 ? Lt : Rt;

    if (ph) __syncthreads();
#pragma unroll
    for (int q = 0; q < 4; ++q) {
      int s = q * 512 + tid;
      int row = s >> 4;
      int j = (s & 15) ^ (row & 7);
      gld_lds16(wp + s * 8, wtp + row * 128 + j * 8);
    }
    if (ph < 2) {
#pragma unroll
      for (int q = 0; q < 4; ++q) {
        int s = q * 512 + tid;
        int row = s >> 4;
        int j = (s & 15) ^ (row & 7);
        gld_lds16(wg + s * 8, wtg + row * 128 + j * 8);
      }
    }
    __syncthreads();

    f32x4_t ap[2][4], ag[2][4];
#pragma unroll
    for (int m = 0; m < 2; ++m)
#pragma unroll
      for (int n = 0; n < 4; ++n) {
        ap[m][n] = (f32x4_t){0.f, 0.f, 0.f, 0.f};
        ag[m][n] = (f32x4_t){0.f, 0.f, 0.f, 0.f};
      }

#pragma unroll
    for (int kt = 0; kt < 4; ++kt) {
      int kb = kt * 4 + lk;
      bf16x8_t af[2], bp_[4], bg_[4];
#pragma unroll
      for (int m = 0; m < 2; ++m) {
        int row = wr * 32 + m * 16 + lr;
        af[m] = *(const bf16x8_t*)(xs + row * 128 + ((kb ^ (row & 7)) * 8));
      }
#pragma unroll
      for (int n = 0; n < 4; ++n) {
        int orow = wc * 64 + n * 16 + lr;
        bp_[n] = *(const bf16x8_t*)(wp + orow * 128 + ((kb ^ (orow & 7)) * 8));
      }
      if (ph < 2) {
#pragma unroll
        for (int n = 0; n < 4; ++n) {
          int orow = wc * 64 + n * 16 + lr;
          bg_[n] = *(const bf16x8_t*)(wg + orow * 128 + ((kb ^ (orow & 7)) * 8));
        }
      }
#pragma unroll
      for (int m = 0; m < 2; ++m)
#pragma unroll
        for (int n = 0; n < 4; ++n)
          ap[m][n] = __builtin_amdgcn_mfma_f32_16x16x32_bf16(af[m], bp_[n], ap[m][n], 0, 0, 0);
      if (ph < 2) {
#pragma unroll
        for (int m = 0; m < 2; ++m)
#pragma unroll
          for (int n = 0; n < 4; ++n)
            ag[m][n] = __builtin_amdgcn_mfma_f32_16x16x32_bf16(af[m], bg_[n], ag[m][n], 0, 0, 0);
      }
    }
    __syncthreads();

    if (ph < 2) {
      float bpv[4], bgv[4];
#pragma unroll
      for (int n = 0; n < 4; ++n) {
        int o = wc * 64 + n * 16 + lr;
        bpv[n] = Bp[o];
        bgv[n] = Bg[o];
      }
#pragma unroll
      for (int m = 0; m < 2; ++m) {
        int p4 = wr * 32 + m * 16 + lk * 4;
        float4 mk = *(const float4*)(mask + p0 + p4);
#pragma unroll
        for (int n = 0; n < 4; ++n) {
          int o = wc * 64 + n * 16 + lr;
          ushort4 v;
          v.x = f2bf(mk.x * (ap[m][n][0] + bpv[n]) * sigm(ag[m][n][0] + bgv[n]));
          v.y = f2bf(mk.y * (ap[m][n][1] + bpv[n]) * sigm(ag[m][n][1] + bgv[n]));
          v.z = f2bf(mk.z * (ap[m][n][2] + bpv[n]) * sigm(ag[m][n][2] + bgv[n]));
          v.w = f2bf(mk.w * (ap[m][n][3] + bpv[n]) * sigm(ag[m][n][3] + bgv[n]));
          *(ushort4*)(ob + o * 136 + p4) = v;
        }
      }
      __syncthreads();
#pragma unroll
      for (int it = 0; it < 4; ++it) {
        int s = it * 512 + tid;
        int o = s >> 4, c8 = s & 15;
        *(uint4*)(Tdst + (size_t)o * NN_ + (size_t)i_row * 512 + j0 + c8 * 8) =
            *(const uint4*)(ob + o * 136 + c8 * 8);
      }
    } else {
      float bpv[4];
#pragma unroll
      for (int n = 0; n < 4; ++n) bpv[n] = Bp[wc * 64 + n * 16 + lr];
#pragma unroll
      for (int m = 0; m < 2; ++m) {
        int p4 = wr * 32 + m * 16 + lk * 4;
#pragma unroll
        for (int n = 0; n < 4; ++n) {
          int o = wc * 64 + n * 16 + lr;
#pragma unroll
          for (int r = 0; r < 4; ++r)
            Gs[(p0 + p4 + r) * 128 + o] = f2bf(sigm(ap[m][n][r] + bpv[n]));
        }
      }
    }
  }
}

// ---------------------------------------------------------------------------
// K3 (MFMA): per-channel NT GEMM (verified R3 — unchanged).
// ---------------------------------------------------------------------------
__global__ __launch_bounds__(256) void k3_einsum_mfma(const u16* __restrict__ Lt,
                                                      const u16* __restrict__ Rt,
                                                      u16* __restrict__ Ot) {
  __shared__ __align__(16) u16 smem[2 * 128 * 64];
  u16* La = smem;
  u16* Rb = smem + 128 * 64;

  int tid = threadIdx.x;
  int bx = blockIdx.x;
  int c = bx >> 4;
  int t = bx & 15;
  int i0 = (t >> 2) << 7, j0 = (t & 3) << 7;
  const u16* Lg = Lt + (size_t)c * NN_ + (size_t)i0 * 512;
  const u16* Rg = Rt + (size_t)c * NN_ + (size_t)j0 * 512;

  int l = tid & 63, w = tid >> 6;
  int wr = w >> 1, wc = w & 1;
  int lr = l & 15, lk = l >> 4;

  f32x4_t acc[4][4];
#pragma unroll
  for (int m = 0; m < 4; ++m)
#pragma unroll
    for (int n = 0; n < 4; ++n) acc[m][n] = (f32x4_t){0.f, 0.f, 0.f, 0.f};

  for (int kt = 0; kt < 512; kt += 64) {
#pragma unroll
    for (int q = 0; q < 4; ++q) {
      int s = q * 256 + tid;
      int row = s >> 3;
      int k8 = (s & 7) ^ (row & 7);
      gld_lds16(La + s * 8, Lg + (size_t)row * 512 + kt + k8 * 8);
      gld_lds16(Rb + s * 8, Rg + (size_t)row * 512 + kt + k8 * 8);
    }
    __syncthreads();

#pragma unroll
    for (int ks = 0; ks < 2; ++ks) {
      int kb = ks * 4 + lk;
      bf16x8_t af[4], bf[4];
#pragma unroll
      for (int m = 0; m < 4; ++m) {
        int row = wr * 64 + m * 16 + lr;
        af[m] = *(const bf16x8_t*)(La + row * 64 + ((kb ^ (row & 7)) * 8));
      }
#pragma unroll
      for (int n = 0; n < 4; ++n) {
        int row = wc * 64 + n * 16 + lr;
        bf[n] = *(const bf16x8_t*)(Rb + row * 64 + ((kb ^ (row & 7)) * 8));
      }
#pragma unroll
      for (int m = 0; m < 4; ++m)
#pragma unroll
        for (int n = 0; n < 4; ++n)
          acc[m][n] = __builtin_amdgcn_mfma_f32_16x16x32_bf16(af[m], bf[n], acc[m][n], 0, 0, 0);
    }
    __syncthreads();
  }

  u16* ob = smem;
#pragma unroll
  for (int m = 0; m < 4; ++m) {
    int row0 = wr * 64 + m * 16 + lk * 4;
#pragma unroll
    for (int n = 0; n < 4; ++n) {
      int col = (wc * 64 + n * 16 + lr) ^ (lk << 4);
#pragma unroll
      for (int r = 0; r < 4; ++r)
        ob[(row0 + r) * 128 + col] = f2bf(acc[m][n][r]);
    }
  }
  __syncthreads();
#pragma unroll
  for (int it = 0; it < 8; ++it) {
    int s = it * 256 + tid;
    int row = s >> 4, c8 = s & 15;
    int g = (row >> 2) & 3;
    const u16* src = ob + row * 128 + ((c8 * 8) ^ (g << 4));
    *(uint4*)(Ot + (size_t)c * NN_ + (size_t)(i0 + row) * 512 + j0 + c8 * 8) =
        *(const uint4*)src;
  }
}

// ---------------------------------------------------------------------------
// K4 (MFMA): center LN over C + out = LN(.) @ wout + bout, times sigmoid-gate.
// BM=128 positions/block, 512 threads. Ot tile staged linearly (conflict-free
// lane=pos LN reads); LN write does the transpose into swizzled xn[p][c];
// Wt6[o][c] staged like k2_all weights. Epilogue: (acc+bout)*Gs -> f32 out.
// ---------------------------------------------------------------------------
__global__ __launch_bounds__(512, 4) void k4_mfma(const u16* __restrict__ Ot,
                                                  const u16* __restrict__ Gs,
                                                  const u16* __restrict__ Wt6,
                                                  const float* __restrict__ gc,
                                                  const float* __restrict__ bc,
                                                  const float* __restrict__ bout,
                                                  float* __restrict__ out) {
  __shared__ __align__(16) unsigned char smem[70656];
  u16* ot = (u16*)smem;                       // [128 c][128 p] linear; xn overlay
  u16* ws = (u16*)(smem + 32768);             // [128 o][128 c] swizzled
  float* ps = (float*)(smem + 65536);         // [4][128]
  float* pss = (float*)(smem + 67584);        // [4][128]
  float2* munr = (float2*)(smem + 69632);     // [128]

  int tid = threadIdx.x;
  int l = tid & 63, w = tid >> 6;
  int wr = w >> 1, wc = w & 1;
  int lr = l & 15, lk = l >> 4;
  size_t p0 = (size_t)blockIdx.x * 128;
  int i_row = (int)(p0 >> 9);
  int j0 = (int)(p0 & 511);

  // stage Ot tile [c][p] linear + Wt6 [o][c] (swizzled source)
#pragma unroll
  for (int q = 0; q < 4; ++q) {
    int s = q * 512 + tid;
    int cc = s >> 4, j = s & 15;
    gld_lds16(ot + s * 8, Ot + (size_t)cc * NN_ + (size_t)i_row * 512 + j0 + j * 8);
  }
#pragma unroll
  for (int q = 0; q < 4; ++q) {
    int s = q * 512 + tid;
    int o = s >> 4, j = (s & 15) ^ (o & 7);
    gld_lds16(ws + s * 8, Wt6 + o * 128 + j * 8);
  }
  __syncthreads();

  // LN partials: thread (g, pos) reads 32 channels of one position
  int g = tid >> 7, pos = tid & 127;
  float vals[32];
  float s1 = 0.0f, s2 = 0.0f;
#pragma unroll
  for (int m = 0; m < 32; ++m) {
    float v = bf2f(ot[(g * 32 + m) * 128 + pos]);
    vals[m] = v;
    s1 += v;
    s2 += v * v;
  }
  ps[g * 128 + pos] = s1;
  pss[g * 128 + pos] = s2;
  __syncthreads();
  if (tid < 128) {
    float a = ps[tid] + ps[128 + tid] + ps[256 + tid] + ps[384 + tid];
    float b = pss[tid] + pss[128 + tid] + pss[256 + tid] + pss[384 + tid];
    float mu = a * (1.0f / 128.0f);
    float rstd = rsqrtf(b * (1.0f / 128.0f) - mu * mu + 1e-5f);
    munr[tid] = make_float2(mu, rstd);
  }
  __syncthreads();
  float2 mr = munr[pos];

  // normalized transpose write: xn[pos][c] (overlay on ot), swizzled c8
  u16* xn = ot;
#pragma unroll
  for (int mm = 0; mm < 4; ++mm) {
    int c8 = g * 4 + mm;
    ushort4 va, vb;
    int cb = c8 * 8;
    va.x = f2bf((vals[mm * 8 + 0] - mr.x) * mr.y * gc[cb + 0] + bc[cb + 0]);
    va.y = f2bf((vals[mm * 8 + 1] - mr.x) * mr.y * gc[cb + 1] + bc[cb + 1]);
    va.z = f2bf((vals[mm * 8 + 2] - mr.x) * mr.y * gc[cb + 2] + bc[cb + 2]);
    va.w = f2bf((vals[mm * 8 + 3] - mr.x) * mr.y * gc[cb + 3] + bc[cb + 3]);
    vb.x = f2bf((vals[mm * 8 + 4] - mr.x) * mr.y * gc[cb + 4] + bc[cb + 4]);
    vb.y = f2bf((vals[mm * 8 + 5] - mr.x) * mr.y * gc[cb + 5] + bc[cb + 5]);
    vb.z = f2bf((vals[mm * 8 + 6] - mr.x) * mr.y * gc[cb + 6] + bc[cb + 6]);
    vb.w = f2bf((vals[mm * 8 + 7] - mr.x) * mr.y * gc[cb + 7] + bc[cb + 7]);
    int slot = (c8 ^ (pos & 7)) * 8;
    *(ushort4*)(xn + pos * 128 + slot) = va;
    *(ushort4*)(xn + pos * 128 + slot + 4) = vb;
  }
  __syncthreads();

  // MFMA: out[p][o] = xn[p][:] . ws[o][:]
  f32x4_t acc[2][4];
#pragma unroll
  for (int m = 0; m < 2; ++m)
#pragma unroll
    for (int n = 0; n < 4; ++n) acc[m][n] = (f32x4_t){0.f, 0.f, 0.f, 0.f};

#pragma unroll
  for (int kt = 0; kt < 4; ++kt) {
    int kb = kt * 4 + lk;
    bf16x8_t af[2], bf[4];
#pragma unroll
    for (int m = 0; m < 2; ++m) {
      int row = wr * 32 + m * 16 + lr;
      af[m] = *(const bf16x8_t*)(xn + row * 128 + ((kb ^ (row & 7)) * 8));
    }
#pragma unroll
    for (int n = 0; n < 4; ++n) {
      int o = wc * 64 + n * 16 + lr;
      bf[n] = *(const bf16x8_t*)(ws + o * 128 + ((kb ^ (o & 7)) * 8));
    }
#pragma unroll
    for (int m = 0; m < 2; ++m)
#pragma unroll
      for (int n = 0; n < 4; ++n)
        acc[m][n] = __builtin_amdgcn_mfma_f32_16x16x32_bf16(af[m], bf[n], acc[m][n], 0, 0, 0);
  }

  // epilogue: (acc + bout) * sigmoid-gate, f32 stores
#pragma unroll
  for (int n = 0; n < 4; ++n) {
    int o = wc * 64 + n * 16 + lr;
    float bo = bout[o];
#pragma unroll
    for (int m = 0; m < 2; ++m) {
      int p = wr * 32 + m * 16 + lk * 4;
#pragma unroll
      for (int r = 0; r < 4; ++r) {
        size_t pg = p0 + p + r;
        float gate = bf2f(Gs[pg * 128 + o]);
        out[pg * 128 + o] = (acc[m][n][r] + bo) * gate;
      }
    }
  }
}

// ---------------------------------------------------------------------------
extern "C" void kernel_launch(void* const* d_in, const int* in_sizes, int n_in,
                              void* d_out, int out_size, void* d_ws, size_t ws_size,
                              hipStream_t stream) {
  const float* act    = (const float*)d_in[0];
  const float* mask   = (const float*)d_in[1];
  const float* ln_in_g = (const float*)d_in[2];
  const float* ln_in_b = (const float*)d_in[3];
  const float* wl     = (const float*)d_in[4];
  const float* bl     = (const float*)d_in[5];
  const float* wr     = (const float*)d_in[6];
  const float* br     = (const float*)d_in[7];
  const float* wgl    = (const float*)d_in[8];
  const float* bgl    = (const float*)d_in[9];
  const float* wgr    = (const float*)d_in[10];
  const float* bgr    = (const float*)d_in[11];
  const float* wgate  = (const float*)d_in[12];
  const float* bgate  = (const float*)d_in[13];
  const float* ln_c_g = (const float*)d_in[14];
  const float* ln_c_b = (const float*)d_in[15];
  const float* wout   = (const float*)d_in[16];
  const float* bout   = (const float*)d_in[17];
  float* out = (float*)d_out;

  char* ws = (char*)d_ws;
  const size_t SEG = 1ull << 26;  // 64 MiB per bf16 [128][512][512] buffer
  u16* Lt  = (u16*)(ws);
  u16* Rt  = (u16*)(ws + 1 * SEG);
  u16* Gs  = (u16*)(ws + 2 * SEG);
  u16* Ot  = (u16*)(ws + 3 * SEG);
  u16* xln = Ot;   // alias: xln lifetime [K1,K2], Ot lifetime [K3,K4]
  u16* Wt6 = Lt;   // alias: Lt dead after k3; k0b writes, k4 reads

  // Wt scratch for the 5 projection weights in the tail of d_out
  // (read only by k2_all; k4 later rewrites all of out).
  u16* wtbase = (u16*)((char*)d_out + (size_t)out_size * 4 - 5 * 32768);

  k0_wt<<<dim3(40), dim3(256), 0, stream>>>(wl, wgl, wr, wgr, wgate, wtbase);
  k1_ln<<<dim3(65536), dim3(256), 0, stream>>>(act, ln_in_g, ln_in_b, xln);
  k2_all<<<dim3(2048), dim3(512), 0, stream>>>(xln, mask, wtbase, bl, bgl, br, bgr,
                                               bgate, Lt, Rt, Gs);
  k3_einsum_mfma<<<dim3(2048), dim3(256), 0, stream>>>(Lt, Rt, Ot);
  k0b<<<dim3(8), dim3(256), 0, stream>>>(wout, Wt6);
  k4_mfma<<<dim3(2048), dim3(512), 0, stream>>>(Ot, Gs, Wt6, ln_c_g, ln_c_b, bout, out);
}